// Round 1
// baseline (1772.567 us; speedup 1.0000x reference)
//
#include <hip/hip_runtime.h>

#define B_TOTAL 65536
#define T_STEPS 28

__device__ __forceinline__ float frcp(float x) { return __builtin_amdgcn_rcpf(x); }
__device__ __forceinline__ float sigf(float x) { return frcp(1.0f + __expf(-x)); }
__device__ __forceinline__ float tanhf_(float x) { return 2.0f * frcp(1.0f + __expf(-2.0f * x)) - 1.0f; }

// One thread per batch element. Weights gate-interleaved (i,f,g,o) as float4 in LDS:
// one broadcast ds_read_b128 -> 4 FMAs. All LSTM state in registers (fully unrolled).
__global__ __launch_bounds__(256, 1)
void lstm_ae_kernel(const float* __restrict__ x,
                    const float* __restrict__ eWih, const float* __restrict__ eWhh,
                    const float* __restrict__ eb,
                    const float* __restrict__ dWih, const float* __restrict__ dWhh,
                    const float* __restrict__ db,
                    const float* __restrict__ UW, const float* __restrict__ Ub,
                    float* __restrict__ out, float* __restrict__ pred)
{
    __shared__ float4 sEncW[4][28];   // enc Wih, [k][j] -> gates (rows k,4+k,8+k,12+k), col j
    __shared__ float4 sEncU[4][4];    // enc Whh
    __shared__ float4 sEncB[4];       // enc bias
    __shared__ float4 sDecI[28][4];   // dec Wih, [k][j], j over 4 enc-hidden dims
    __shared__ float4 sDecW[28][28];  // dec Whh, [k][j]
    __shared__ float4 sDecB[28];      // dec bias
    __shared__ float  sUW[280];       // U_W [10][28] flat
    __shared__ float  sUB[10];

    const int tid = threadIdx.x;

    for (int p = tid; p < 4 * 28; p += 256) {
        int k = p / 28, j = p % 28;
        sEncW[k][j] = make_float4(eWih[k * 28 + j], eWih[(4 + k) * 28 + j],
                                  eWih[(8 + k) * 28 + j], eWih[(12 + k) * 28 + j]);
    }
    if (tid < 16) {
        int k = tid / 4, j = tid % 4;
        sEncU[k][j] = make_float4(eWhh[k * 4 + j], eWhh[(4 + k) * 4 + j],
                                  eWhh[(8 + k) * 4 + j], eWhh[(12 + k) * 4 + j]);
    }
    if (tid < 4) sEncB[tid] = make_float4(eb[tid], eb[4 + tid], eb[8 + tid], eb[12 + tid]);
    for (int p = tid; p < 28 * 4; p += 256) {
        int k = p / 4, j = p % 4;
        sDecI[k][j] = make_float4(dWih[k * 4 + j], dWih[(28 + k) * 4 + j],
                                  dWih[(56 + k) * 4 + j], dWih[(84 + k) * 4 + j]);
    }
    for (int p = tid; p < 28 * 28; p += 256) {
        int k = p / 28, j = p % 28;
        sDecW[k][j] = make_float4(dWhh[k * 28 + j], dWhh[(28 + k) * 28 + j],
                                  dWhh[(56 + k) * 28 + j], dWhh[(84 + k) * 28 + j]);
    }
    if (tid < 28) sDecB[tid] = make_float4(db[tid], db[28 + tid], db[56 + tid], db[84 + tid]);
    for (int p = tid; p < 280; p += 256) sUW[p] = UW[p];
    if (tid < 10) sUB[tid] = Ub[tid];
    __syncthreads();

    const int e = blockIdx.x * 256 + tid;
    const float4* __restrict__ xv = reinterpret_cast<const float4*>(x + (size_t)e * 784);
    float4* __restrict__ ov       = reinterpret_cast<float4*>(out + (size_t)e * 784);

    float he[4] = {0.f, 0.f, 0.f, 0.f}, ce[4] = {0.f, 0.f, 0.f, 0.f};
    float hd[28], cd[28];
#pragma unroll
    for (int k = 0; k < 28; k++) { hd[k] = 0.f; cd[k] = 0.f; }

    float4 xt[7];
#pragma unroll
    for (int q = 0; q < 7; q++) xt[q] = xv[q];

    for (int t = 0; t < T_STEPS; ++t) {
        // ---------- encoder step ----------
        float hen[4];
#pragma unroll
        for (int k = 0; k < 4; k++) {
            float4 a = sEncB[k];
#pragma unroll
            for (int q = 0; q < 7; q++) {
                float4 xx = xt[q];
                float4 w;
                w = sEncW[k][4 * q + 0]; a.x += w.x * xx.x; a.y += w.y * xx.x; a.z += w.z * xx.x; a.w += w.w * xx.x;
                w = sEncW[k][4 * q + 1]; a.x += w.x * xx.y; a.y += w.y * xx.y; a.z += w.z * xx.y; a.w += w.w * xx.y;
                w = sEncW[k][4 * q + 2]; a.x += w.x * xx.z; a.y += w.y * xx.z; a.z += w.z * xx.z; a.w += w.w * xx.z;
                w = sEncW[k][4 * q + 3]; a.x += w.x * xx.w; a.y += w.y * xx.w; a.z += w.z * xx.w; a.w += w.w * xx.w;
            }
#pragma unroll
            for (int j = 0; j < 4; j++) {
                float4 w = sEncU[k][j]; float hh = he[j];
                a.x += w.x * hh; a.y += w.y * hh; a.z += w.z * hh; a.w += w.w * hh;
            }
            float cc = sigf(a.y) * ce[k] + sigf(a.x) * tanhf_(a.z);
            ce[k] = cc;
            hen[k] = sigf(a.w) * tanhf_(cc);
        }
#pragma unroll
        for (int k = 0; k < 4; k++) he[k] = hen[k];

        // prefetch next timestep's x while decoder computes
        if (t < T_STEPS - 1) {
#pragma unroll
            for (int q = 0; q < 7; q++) xt[q] = xv[(t + 1) * 7 + q];
        }

        // ---------- decoder step ----------
        float hn[28];
#pragma unroll
        for (int k = 0; k < 28; k++) {
            float4 a = sDecB[k];
#pragma unroll
            for (int j = 0; j < 4; j++) {
                float4 w = sDecI[k][j]; float zz = he[j];
                a.x += w.x * zz; a.y += w.y * zz; a.z += w.z * zz; a.w += w.w * zz;
            }
#pragma unroll
            for (int j = 0; j < 28; j++) {
                float4 w = sDecW[k][j]; float hh = hd[j];
                a.x += w.x * hh; a.y += w.y * hh; a.z += w.z * hh; a.w += w.w * hh;
            }
            float cc = sigf(a.y) * cd[k] + sigf(a.x) * tanhf_(a.z);
            cd[k] = cc;
            hn[k] = sigf(a.w) * tanhf_(cc);
        }
#pragma unroll
        for (int k = 0; k < 28; k++) hd[k] = hn[k];

        // store out[e][t][0:28]
#pragma unroll
        for (int q = 0; q < 7; q++)
            ov[t * 7 + q] = make_float4(hd[4 * q], hd[4 * q + 1], hd[4 * q + 2], hd[4 * q + 3]);
    }

    // ---------- final projection + softmax ----------
    float lg[10];
#pragma unroll
    for (int c = 0; c < 10; c++) {
        float a = sUB[c];
#pragma unroll
        for (int j = 0; j < 28; j++) a += sUW[c * 28 + j] * hd[j];
        lg[c] = a;
    }
    float m = lg[0];
#pragma unroll
    for (int c = 1; c < 10; c++) m = fmaxf(m, lg[c]);
    float s = 0.f;
#pragma unroll
    for (int c = 0; c < 10; c++) { lg[c] = __expf(lg[c] - m); s += lg[c]; }
    float inv = frcp(s);
    float* __restrict__ pr = pred + (size_t)e * 10;
#pragma unroll
    for (int c = 0; c < 10; c++) pr[c] = lg[c] * inv;
}

extern "C" void kernel_launch(void* const* d_in, const int* in_sizes, int n_in,
                              void* d_out, int out_size, void* d_ws, size_t ws_size,
                              hipStream_t stream) {
    const float* x    = (const float*)d_in[0];
    const float* eWih = (const float*)d_in[1];
    const float* eWhh = (const float*)d_in[2];
    const float* eb   = (const float*)d_in[3];
    const float* dWih = (const float*)d_in[4];
    const float* dWhh = (const float*)d_in[5];
    const float* db   = (const float*)d_in[6];
    const float* UW   = (const float*)d_in[7];
    const float* Ub   = (const float*)d_in[8];

    float* out  = (float*)d_out;
    float* pred = out + (size_t)B_TOTAL * T_STEPS * 28;

    lstm_ae_kernel<<<dim3(B_TOTAL / 256), dim3(256), 0, stream>>>(
        x, eWih, eWhh, eb, dWih, dWhh, db, UW, Ub, out, pred);
}

// Round 2
// 916.889 us; speedup vs baseline: 1.9332x; 1.9332x over previous
//
#include <hip/hip_runtime.h>

#define B_TOTAL 65536
#define T_STEPS 28

__device__ __forceinline__ float frcp(float x) { return __builtin_amdgcn_rcpf(x); }
__device__ __forceinline__ float sigf(float x) { return frcp(1.0f + __expf(-x)); }
__device__ __forceinline__ float tanhf_(float x) { return 2.0f * frcp(1.0f + __expf(-2.0f * x)) - 1.0f; }

// ---------------------------------------------------------------------------
// Repack weights into wave-uniform scalar-load-friendly rows in d_ws.
// Row format (132 floats): [b_i b_f b_g b_o][Wi 0..31][Wf 0..31][Wg 0..31][Wo 0..31]
//   enc row k (k=0..3):   inputs = [x(28), he_prev(4)]  -> W*[j<28]=Wih, W*[28+j]=Whh
//   dec row k (rows 4..31): inputs = [hd(28), z(4)]     -> W*[j<28]=Whh, W*[28+j]=Wih
// U rows at float offset 4224, stride 32: [bias][UW 28][pad 3]
// ---------------------------------------------------------------------------
__global__ void repack_kernel(const float* __restrict__ eWih, const float* __restrict__ eWhh,
                              const float* __restrict__ eb,
                              const float* __restrict__ dWih, const float* __restrict__ dWhh,
                              const float* __restrict__ db,
                              const float* __restrict__ UW, const float* __restrict__ Ub,
                              float* __restrict__ w)
{
    const int p = threadIdx.x;
    for (int idx = p; idx < 4 * 132; idx += 256) {
        int k = idx / 132, r = idx % 132;
        float v;
        if (r < 4) v = eb[r * 4 + k];
        else {
            int g = (r - 4) / 32, j = (r - 4) % 32;
            v = (j < 28) ? eWih[(g * 4 + k) * 28 + j] : eWhh[(g * 4 + k) * 4 + (j - 28)];
        }
        w[k * 132 + r] = v;
    }
    for (int idx = p; idx < 28 * 132; idx += 256) {
        int k = idx / 132, r = idx % 132;
        float v;
        if (r < 4) v = db[r * 28 + k];
        else {
            int g = (r - 4) / 32, j = (r - 4) % 32;
            v = (j < 28) ? dWhh[(g * 28 + k) * 28 + j] : dWih[(g * 28 + k) * 4 + (j - 28)];
        }
        w[528 + k * 132 + r] = v;
    }
    for (int idx = p; idx < 10 * 32; idx += 256) {
        int c = idx / 32, r = idx % 32;
        float v = (r == 0) ? Ub[c] : ((r <= 28) ? UW[c * 28 + (r - 1)] : 0.f);
        w[4224 + c * 32 + r] = v;
    }
}

// ---------------------------------------------------------------------------
// Main kernel: block = 256 threads = 4 waves covering 64 elements.
// Wave s: encoder unit s + decoder rows s*7..s*7+6. Weights via uniform
// (scalar) loads from repacked w; h-state exchanged through LDS.
// ---------------------------------------------------------------------------
__global__ __launch_bounds__(256, 4)
void lstm_main(const float* __restrict__ x, const float* __restrict__ w,
               float* __restrict__ out, float* __restrict__ pred)
{
    __shared__ float hdBuf[28][64];
    __shared__ float heBuf[2][4][64];

    const int lane = threadIdx.x & 63;
    const int s    = __builtin_amdgcn_readfirstlane(threadIdx.x >> 6);
    const int e    = blockIdx.x * 64 + lane;

    const float* __restrict__ xp = x + (size_t)e * 784;
    float* __restrict__ op       = out + (size_t)e * 784;

    // zero-init shared state
    for (int j = s; j < 28; j += 4) hdBuf[j][lane] = 0.f;
    if (s == 0) {
        heBuf[0][0][lane] = 0.f; heBuf[0][1][lane] = 0.f;
        heBuf[0][2][lane] = 0.f; heBuf[0][3][lane] = 0.f;
    }
    __syncthreads();

    const float* __restrict__ wenc = w + s * 132;

    float ce = 0.f;
    float cd[7];
#pragma unroll
    for (int r = 0; r < 7; r++) cd[r] = 0.f;

    float4 xt[7];
#pragma unroll
    for (int q = 0; q < 7; q++) xt[q] = reinterpret_cast<const float4*>(xp)[q];

    for (int t = 0; t < T_STEPS; ++t) {
        const int p = t & 1;

        // ---- phase 1: read prev state from LDS ----
        float hd[28];
#pragma unroll
        for (int j = 0; j < 28; j++) hd[j] = hdBuf[j][lane];
        float hep[4];
#pragma unroll
        for (int g = 0; g < 4; g++) hep[g] = heBuf[p][g][lane];

        // ---- phase 2: encoder row s ----
        {
            float ai = wenc[0], af = wenc[1], ag = wenc[2], ao = wenc[3];
            const float* __restrict__ W = wenc + 4;
#pragma unroll
            for (int q = 0; q < 7; q++) {
                const float xv0 = xt[q].x, xv1 = xt[q].y, xv2 = xt[q].z, xv3 = xt[q].w;
                const int j = 4 * q;
                ai = fmaf(W[j], xv0, ai);      af = fmaf(W[32 + j], xv0, af);
                ag = fmaf(W[64 + j], xv0, ag); ao = fmaf(W[96 + j], xv0, ao);
                ai = fmaf(W[j + 1], xv1, ai);      af = fmaf(W[33 + j], xv1, af);
                ag = fmaf(W[65 + j], xv1, ag); ao = fmaf(W[97 + j], xv1, ao);
                ai = fmaf(W[j + 2], xv2, ai);      af = fmaf(W[34 + j], xv2, af);
                ag = fmaf(W[66 + j], xv2, ag); ao = fmaf(W[98 + j], xv2, ao);
                ai = fmaf(W[j + 3], xv3, ai);      af = fmaf(W[35 + j], xv3, af);
                ag = fmaf(W[67 + j], xv3, ag); ao = fmaf(W[99 + j], xv3, ao);
            }
#pragma unroll
            for (int j = 0; j < 4; j++) {
                const float hv = hep[j];
                ai = fmaf(W[28 + j], hv, ai); af = fmaf(W[60 + j], hv, af);
                ag = fmaf(W[92 + j], hv, ag); ao = fmaf(W[124 + j], hv, ao);
            }
            ce = sigf(af) * ce + sigf(ai) * tanhf_(ag);
            heBuf[p ^ 1][s][lane] = sigf(ao) * tanhf_(ce);
        }
        __syncthreads();

        // ---- phase 3: decoder input z = he_new ----
        float hz[4];
#pragma unroll
        for (int g = 0; g < 4; g++) hz[g] = heBuf[p ^ 1][g][lane];

        // ---- phase 4: decoder rows s*7 .. s*7+6 ----
#pragma unroll
        for (int r = 0; r < 7; r++) {
            const int k = s * 7 + r;
            const float* __restrict__ wrow = w + 528 + k * 132;
            float ai = wrow[0], af = wrow[1], ag = wrow[2], ao = wrow[3];
            const float* __restrict__ W = wrow + 4;
#pragma unroll
            for (int j = 0; j < 28; j++) {
                const float hv = hd[j];
                ai = fmaf(W[j], hv, ai);      af = fmaf(W[32 + j], hv, af);
                ag = fmaf(W[64 + j], hv, ag); ao = fmaf(W[96 + j], hv, ao);
            }
#pragma unroll
            for (int j = 0; j < 4; j++) {
                const float zv = hz[j];
                ai = fmaf(W[28 + j], zv, ai); af = fmaf(W[60 + j], zv, af);
                ag = fmaf(W[92 + j], zv, ag); ao = fmaf(W[124 + j], zv, ao);
            }
            const float cc = sigf(af) * cd[r] + sigf(ai) * tanhf_(ag);
            cd[r] = cc;
            const float hh = sigf(ao) * tanhf_(cc);
            hdBuf[k][lane] = hh;
            op[t * 28 + s * 7 + r] = hh;
        }

        // prefetch next timestep's x (112B stride is 16B-aligned)
        if (t < T_STEPS - 1) {
#pragma unroll
            for (int q = 0; q < 7; q++)
                xt[q] = reinterpret_cast<const float4*>(xp + (t + 1) * 28)[q];
        }
        __syncthreads();
    }

    // ---- final projection + softmax (wave 0 only) ----
    if (s == 0) {
        float hf[28];
#pragma unroll
        for (int j = 0; j < 28; j++) hf[j] = hdBuf[j][lane];
        float lg[10];
#pragma unroll
        for (int c = 0; c < 10; c++) {
            const float* __restrict__ ur = w + 4224 + c * 32;
            float a = ur[0];
#pragma unroll
            for (int j = 0; j < 28; j++) a = fmaf(ur[1 + j], hf[j], a);
            lg[c] = a;
        }
        float m = lg[0];
#pragma unroll
        for (int c = 1; c < 10; c++) m = fmaxf(m, lg[c]);
        float sum = 0.f;
#pragma unroll
        for (int c = 0; c < 10; c++) { lg[c] = __expf(lg[c] - m); sum += lg[c]; }
        const float inv = frcp(sum);
        float* __restrict__ pr = pred + (size_t)e * 10;
#pragma unroll
        for (int c = 0; c < 10; c++) pr[c] = lg[c] * inv;
    }
}

extern "C" void kernel_launch(void* const* d_in, const int* in_sizes, int n_in,
                              void* d_out, int out_size, void* d_ws, size_t ws_size,
                              hipStream_t stream) {
    const float* x    = (const float*)d_in[0];
    const float* eWih = (const float*)d_in[1];
    const float* eWhh = (const float*)d_in[2];
    const float* eb   = (const float*)d_in[3];
    const float* dWih = (const float*)d_in[4];
    const float* dWhh = (const float*)d_in[5];
    const float* db   = (const float*)d_in[6];
    const float* UW   = (const float*)d_in[7];
    const float* Ub   = (const float*)d_in[8];

    float* w    = (float*)d_ws;                      // 4544 floats used
    float* out  = (float*)d_out;
    float* pred = out + (size_t)B_TOTAL * T_STEPS * 28;

    repack_kernel<<<dim3(1), dim3(256), 0, stream>>>(eWih, eWhh, eb, dWih, dWhh, db, UW, Ub, w);
    lstm_main<<<dim3(B_TOTAL / 64), dim3(256), 0, stream>>>(x, w, out, pred);
}